// Round 1
// baseline (219.363 us; speedup 1.0000x reference)
//
#include <hip/hip_runtime.h>
#include <hip/hip_bf16.h>
#include <math.h>

#define SEQ 2048
#define EMB 256
#define DIN 264   // EMB + HID
#define TAGS 50
#define INV2PI 0.15915494309189535f
#define CHLEN 8     // output steps per chunk/block -> 256 blocks = 1/CU
#define WARM 48     // 0.79^48 ~ 1.2e-5 residual << bf16 output quantization (0.0156)
#define NCHUNK (SEQ / CHLEN)       // 256 blocks
#define PRE_ROWS 64                // WARM+CHLEN (=56) + 8 prefetch slack

typedef unsigned v2u __attribute__((ext_vector_type(2)));

#if defined(__has_builtin)
#if __has_builtin(__builtin_amdgcn_permlane32_swap) && __has_builtin(__builtin_amdgcn_permlane16_swap)
#define HAVE_PLSWAP 1
#endif
#endif
#ifndef HAVE_PLSWAP
#define HAVE_PLSWAP 0
#endif

// dtype-flexible load: F32 ? float32 : bf16
template<bool F32>
__device__ __forceinline__ float ldf(const void* p, int i) {
    if constexpr (F32) {
        return ((const float*)p)[i];
    } else {
        unsigned int u = ((const unsigned short*)p)[i];
        return __uint_as_float(u << 16);
    }
}

// 8 consecutive elements via 16B vector loads (row starts are 16B aligned:
// DIN*elt_size multiples of 16; offs multiple of 8 elements)
template<bool F32>
__device__ __forceinline__ void ld8(const void* p, int elem_off, float* out) {
    if constexpr (F32) {
        const float4* q = (const float4*)((const float*)p + elem_off);
        float4 a = q[0], b = q[1];
        out[0]=a.x; out[1]=a.y; out[2]=a.z; out[3]=a.w;
        out[4]=b.x; out[5]=b.y; out[6]=b.z; out[7]=b.w;
    } else {
        const uint4* q = (const uint4*)((const unsigned short*)p + elem_off);
        uint4 a = q[0];
        out[0]=__uint_as_float(a.x << 16); out[1]=__uint_as_float(a.x & 0xFFFF0000u);
        out[2]=__uint_as_float(a.y << 16); out[3]=__uint_as_float(a.y & 0xFFFF0000u);
        out[4]=__uint_as_float(a.z << 16); out[5]=__uint_as_float(a.z & 0xFFFF0000u);
        out[6]=__uint_as_float(a.w << 16); out[7]=__uint_as_float(a.w & 0xFFFF0000u);
    }
}

// Per-wave dtype probe on raw 16-bit halves of emb (R2-proven).
__device__ __forceinline__ bool probe_f32(const void* emb) {
    unsigned short v = ((const unsigned short*)emb)[threadIdx.x & 63];
    int ex = (v >> 7) & 0xFF;
    bool bad = (ex == 0xFF) || (ex > 130) || (ex != 0 && ex < 100);
    return __popcll(__ballot(bad)) > 5;
}

// Pade [5/4] tanh: err < 3e-5 on [-2.2,2.2] (cell: |cx| <= ~2.1)
__device__ __forceinline__ float pade_tanh(float x) {
    float u = x * x;
    float num = x * fmaf(u, fmaf(u, 1.0f, 105.0f), 945.0f);
    float den = fmaf(u, fmaf(u, 15.0f, 420.0f), 945.0f);
    return num * __builtin_amdgcn_rcpf(den);
}

// Pade [3/2] tanh: err < 3.2e-4 on [-1,1] (activation: |arg| <= 1)
__device__ __forceinline__ float tanh32(float x) {
    float u = x * x;
    float num = x * (u + 15.0f);
    float den = fmaf(u, 6.0f, 15.0f);
    return num * __builtin_amdgcn_rcpf(den);
}

template<int CTRL>
__device__ __forceinline__ float dpp_shr(float x) {
    return __int_as_float(__builtin_amdgcn_update_dpp(
        0, __float_as_int(x), CTRL, 0xF, 0xF, true));
}
template<int N>
__device__ __forceinline__ float dpp_shl(float x) {
    return __int_as_float(__builtin_amdgcn_update_dpp(
        0, __float_as_int(x), 0x100 | N, 0xF, 0xF, true));
}
// row_shr:4 with multiplicative-identity masking (R4-proven)
__device__ __forceinline__ float dpp_shr4_id(float x) {
    return __int_as_float(__builtin_amdgcn_update_dpp(
        __float_as_int(1.0f), __float_as_int(x), 0x114, 0xF, 0xB, false));
}
__device__ __forceinline__ float bperm(int byteidx, float v) {
    return __int_as_float(__builtin_amdgcn_ds_bpermute(byteidx, __float_as_int(v)));
}
__device__ __forceinline__ float rdlane(float v, int l) {
    return __int_as_float(__builtin_amdgcn_readlane(__float_as_int(v), l));
}

// ---------------- Phase B: recurrence over LDS-resident pre ----------------
// Identical math to the R6-proven seq_loop; pre source is LDS (local step idx).
template<bool F32, bool FAST>
__device__ __forceinline__ void seq_loop_lds(
    const float* pre_lds, float* hlds,
    const float (&Wh)[8], int pidx, int k,
    float as, float os, float ob,
    int bfi, int bii, int bui, int boi, bool sel32, bool sel16,
    int nst, int warm)
{
    const int lane = threadIdx.x;
    const bool k1 = (k >= 1), k2 = (k >= 2);
    const bool isk0 = (k == 0);
    float h0 = 0.f, h1 = 0.f, h2 = 0.f, h3 = 0.f;
    float h4 = 0.f, h5 = 0.f, h6 = 0.f, h7 = 0.f;
    float cx = 0.f;
    const float* pp = pre_lds + pidx;
    float pb[8];
    #pragma unroll
    for (int i = 0; i < 8; ++i) pb[i] = pp[i * 32];
    pp += 8 * 32;

    for (int tb = 0; tb < nst; tb += 8) {     // nst always a multiple of 8
        #pragma unroll
        for (int u = 0; u < 8; ++u) {
            float pv = pb[u];
            pb[u] = pp[u * 32];   // prefetch +8; tail hits slack rows, unused
            // phi/2pi = pv + (Wh/2pi).h
            float a0 = fmaf(h0, Wh[0], pv);
            float a1 = fmaf(h1, Wh[1], h2 * Wh[2]);
            float a2 = fmaf(h3, Wh[3], h4 * Wh[4]);
            float a3 = fmaf(h5, Wh[5], h6 * Wh[6]);
            float phi = (a1 + a2) + (a3 + fmaf(h7, Wh[7], a0));
            float c = __builtin_amdgcn_cosf(phi);     // input in revolutions
            // inclusive product scan over 8-lane groups (row-local DPP)
            float d = c;
            float t1 = dpp_shr<0x111>(d); d *= (k1 ? t1 : 1.0f);
            float t2 = dpp_shr<0x112>(d); d *= (k2 ? t2 : 1.0f);
            d *= dpp_shr4_id(d);
            // activation: ob + os*tanh(as*outv)
            float act = fmaf(os, tanh32(d * as), ob);
            float f_, iv, uv, ov;
            if constexpr (FAST) {
                v2u r32 = __builtin_amdgcn_permlane32_swap(
                    __float_as_uint(act), __float_as_uint(act), false, false);
                float up = __uint_as_float(sel32 ? r32[1] : r32[0]); // old upper half
                float fix = dpp_shl<6>(up);              // lane 8g <- up[8g+6]
                float act0 = isk0 ? fix : act;
                v2u r16 = __builtin_amdgcn_permlane16_swap(
                    __float_as_uint(act0), __float_as_uint(act0), false, false);
                float sw = __uint_as_float(sel16 ? r16[1] : r16[0]); // row1 -> row0
                f_ = act0;               // lanes 0-7: f
                iv = dpp_shl<8>(act0);   // lanes 0-7 <- 8-15: i
                uv = sw;                 // lanes 0-7 <- 16-23: u
                ov = dpp_shl<8>(sw);     // lanes 0-7 <- 24-31: o
            } else {
                f_ = bperm(bfi, act);
                iv = bperm(bii, act);
                uv = bperm(bui, act);
                ov = bperm(boi, act);
            }
            cx = fmaf(f_, cx, iv * uv);
            float th = pade_tanh(cx);
            float hv = ov * th;
            int idx = tb + u - warm;              // warm steps clamp to slot 0
            idx = idx < 0 ? 0 : idx;
            if (lane < 8) hlds[idx * 8 + lane] = hv;
            h0 = rdlane(hv, 0); h1 = rdlane(hv, 1);
            h2 = rdlane(hv, 2); h3 = rdlane(hv, 3);
            h4 = rdlane(hv, 4); h5 = rdlane(hv, 5);
            h6 = rdlane(hv, 6); h7 = rdlane(hv, 7);
        }
        pp += 8 * 32;
    }
}

// ---------------- Fused kernel body ----------------
template<bool F32>
__device__ __forceinline__ void fused_body(
    const int* __restrict__ sentence, const void* __restrict__ emb,
    const void* Wf, const void* bf_, const void* Wi, const void* bi,
    const void* Wu, const void* bu, const void* Wo, const void* bo,
    const void* thf, const void* thi, const void* thu, const void* tho,
    const void* Wt, const void* bt, void* __restrict__ out,
    float* pre_lds, float* hlds)
{
    const int tid = threadIdx.x;
    const int t_out = blockIdx.x * CHLEN;
    const int start = (t_out >= WARM) ? (t_out - WARM) : 0;
    const int nst   = t_out + CHLEN - start;   // multiple of 8 always
    const int warm  = t_out - start;

    // ---- Phase A: pre[tt][32] -> LDS (all 4 waves; 32 units x 8 lanes) ----
    {
        const int u = tid >> 3;
        const int j = tid & 7;
        const int g = u >> 3, w = u & 7;
        const void* W  = (g == 0) ? Wf  : (g == 1) ? Wi  : (g == 2) ? Wu  : Wo;
        const void* b  = (g == 0) ? bf_ : (g == 1) ? bi  : (g == 2) ? bu  : bo;
        const void* th = (g == 0) ? thf : (g == 1) ? thi : (g == 2) ? thu : tho;
        // W row resident in 32 VGPRs for the whole t-loop
        float wv[32];
        #pragma unroll
        for (int m = 0; m < 4; ++m) ld8<F32>(W, w * DIN + j * 8 + m * 64, wv + m * 8);
        const float bias = ldf<F32>(b, w) + ldf<F32>(th, w);

        auto ldrow = [&](int tt, float* ev) {
            const int rw = sentence[start + tt] * EMB;
            #pragma unroll
            for (int m = 0; m < 4; ++m) ld8<F32>(emb, rw + j * 8 + m * 64, ev + m * 8);
        };
        auto consume = [&](int tt, const float* ev) {
            float s = 0.f;
            #pragma unroll
            for (int i = 0; i < 32; ++i) s += ev[i] * wv[i];
            s += __shfl_xor(s, 1, 8);
            s += __shfl_xor(s, 2, 8);
            s += __shfl_xor(s, 4, 8);
            if (j == 0) pre_lds[tt * 32 + u] = (s + bias) * INV2PI;
        };
        // static 2-deep pipeline (named buffers: no runtime indexing -> no scratch)
        float evA[32], evB[32];
        ldrow(0, evA);
        for (int tt = 0; tt < nst; tt += 2) {
            ldrow(tt + 1, evB);
            consume(tt, evA);
            if (tt + 2 < nst) ldrow(tt + 2, evA);
            consume(tt + 1, evB);
        }
    }
    __syncthreads();

    // ---- Phase B: serial recurrence (wave 0 only) ----
    if (tid < 64) {
        const int lane = tid;
        const int k = lane & 7;
        const int g = (lane >> 3) & 3;
        const int w = (lane < 32) ? k : (7 - k);
        const void* W = (g == 0) ? Wf : (g == 1) ? Wi : (g == 2) ? Wu : Wo;
        float Wh[8];
        #pragma unroll
        for (int j = 0; j < 8; ++j) Wh[j] = ldf<F32>(W, w * DIN + EMB + j) * INV2PI;
        const int pidx = (g << 3) | w;
        const float as = (g == 2) ? 1.0f : 0.5f;
        const float os = (g == 2) ? 1.0f : 0.5f;
        const float ob = (g == 2) ? 0.0f : 0.5f;
        // bperm fallback gather indices (lanes 0-7 meaningful)
        const int bfi = ((k == 0) ? 38 : k) << 2;
        const int bii = ((k == 0) ? 46 : (8 + k)) << 2;
        const int bui = ((k == 0) ? 54 : (16 + k)) << 2;
        const int boi = ((k == 0) ? 62 : (24 + k)) << 2;

        bool fast = false, sel32 = false, sel16 = false;
#if HAVE_PLSWAP
        {
            // probe the swap builtins' result ordering with lane ids
            unsigned li = (unsigned)lane;
            v2u r = __builtin_amdgcn_permlane32_swap(li, li, false, false);
            bool gx = (lane >= 32) || (r[0] == li + 32);
            bool gy = (lane >= 32) || (r[1] == li + 32);
            bool ax = __popcll(__ballot(gx)) == 64;
            bool ay = __popcll(__ballot(gy)) == 64;
            sel32 = (!ax && ay);
            bool ok32 = ax || ay;
            v2u s = __builtin_amdgcn_permlane16_swap(li, li, false, false);
            bool rowEven = ((lane >> 4) & 1) == 0;
            bool hx = !rowEven || (s[0] == li + 16);
            bool hy = !rowEven || (s[1] == li + 16);
            bool bx = __popcll(__ballot(hx)) == 64;
            bool by = __popcll(__ballot(hy)) == 64;
            sel16 = (!bx && by);
            bool ok16 = bx || by;
            fast = ok32 && ok16;
        }
#endif
        if (fast) seq_loop_lds<F32, true >(pre_lds, hlds, Wh, pidx, k, as, os, ob,
                                           bfi, bii, bui, boi, sel32, sel16, nst, warm);
        else      seq_loop_lds<F32, false>(pre_lds, hlds, Wh, pidx, k, as, os, ob,
                                           bfi, bii, bui, boi, sel32, sel16, nst, warm);
    }
    __syncthreads();

    // ---- Phase C: head + log_softmax (wave v handles t_local = v, v+4) ----
    {
        const int wvid = tid >> 6;
        const int l = tid & 63;
        #pragma unroll
        for (int rep = 0; rep < CHLEN / 4; ++rep) {
            const int tl = wvid + rep * 4;
            const int t = t_out + tl;
            float hk[8];
            #pragma unroll
            for (int j = 0; j < 8; ++j) hk[j] = hlds[tl * 8 + j];   // LDS broadcast
            float logit = -INFINITY;
            if (l < TAGS) {
                logit = ldf<F32>(bt, l);
                #pragma unroll
                for (int j = 0; j < 8; ++j) logit += hk[j] * ldf<F32>(Wt, l * 8 + j);
            }
            float m = logit;
            #pragma unroll
            for (int s = 32; s >= 1; s >>= 1) m = fmaxf(m, __shfl_xor(m, s, 64));
            float e = (l < TAGS) ? __expf(logit - m) : 0.f;
            float sum = e;
            #pragma unroll
            for (int s = 32; s >= 1; s >>= 1) sum += __shfl_xor(sum, s, 64);
            if (l < TAGS) {
                float v = logit - m - __logf(sum);
                if constexpr (F32) ((float*)out)[t * TAGS + l] = v;
                else ((unsigned short*)out)[t * TAGS + l] =
                         (unsigned short)(((__float_as_uint(v) + 0x8000u +
                                            ((__float_as_uint(v) >> 16) & 1u)) >> 16));  // RNE bf16
            }
        }
    }
}

__global__ __launch_bounds__(256) void k_fused(
    const int* __restrict__ sentence, const void* __restrict__ emb,
    const void* Wf, const void* bf_, const void* Wi, const void* bi,
    const void* Wu, const void* bu, const void* Wo, const void* bo,
    const void* thf, const void* thi, const void* thu, const void* tho,
    const void* Wt, const void* bt, void* __restrict__ out)
{
    __shared__ float pre_lds[PRE_ROWS * 32];   // 8 KiB (56 rows + prefetch slack)
    __shared__ float hlds[CHLEN * 8];          // 256 B
    if (probe_f32(emb))
        fused_body<true >(sentence, emb, Wf, bf_, Wi, bi, Wu, bu, Wo, bo,
                          thf, thi, thu, tho, Wt, bt, out, pre_lds, hlds);
    else
        fused_body<false>(sentence, emb, Wf, bf_, Wi, bi, Wu, bu, Wo, bo,
                          thf, thi, thu, tho, Wt, bt, out, pre_lds, hlds);
}

extern "C" void kernel_launch(void* const* d_in, const int* in_sizes, int n_in,
                              void* d_out, int out_size, void* d_ws, size_t ws_size,
                              hipStream_t stream) {
    (void)in_sizes; (void)n_in; (void)out_size; (void)d_ws; (void)ws_size;
    const int* sentence = (const int*)d_in[0];
    const void* emb = d_in[1];
    const void* Wf = d_in[2];  const void* bf_ = d_in[3];
    const void* Wi = d_in[4];  const void* bi = d_in[5];
    const void* Wu = d_in[6];  const void* bu = d_in[7];
    const void* Wo = d_in[8];  const void* bo = d_in[9];
    const void* thf = d_in[10]; const void* thi = d_in[11];
    const void* thu = d_in[12]; const void* tho = d_in[13];
    const void* Wt = d_in[14]; const void* bt = d_in[15];

    k_fused<<<dim3(NCHUNK), dim3(256), 0, stream>>>(sentence, emb,
        Wf, bf_, Wi, bi, Wu, bu, Wo, bo, thf, thi, thu, tho, Wt, bt, d_out);
}

// Round 3
// 205.099 us; speedup vs baseline: 1.0695x; 1.0695x over previous
//
#include <hip/hip_runtime.h>
#include <hip/hip_bf16.h>
#include <math.h>

#define SEQ 2048
#define EMB 256
#define DIN 264   // EMB + HID
#define TAGS 50
#define INV2PI 0.15915494309189535f
#define CHLEN 8     // output steps per chunk/block -> 256 blocks = 1/CU
#define WARM 48     // 0.79^48 ~ 1.2e-5 residual (harness-validated in R1, same absmax)
#define NCHUNK (SEQ / CHLEN)   // 256 blocks

typedef unsigned v2u __attribute__((ext_vector_type(2)));

#if defined(__has_builtin)
#if __has_builtin(__builtin_amdgcn_permlane32_swap) && __has_builtin(__builtin_amdgcn_permlane16_swap)
#define HAVE_PLSWAP 1
#endif
#endif
#ifndef HAVE_PLSWAP
#define HAVE_PLSWAP 0
#endif

// dtype-flexible load: F32 ? float32 : bf16
template<bool F32>
__device__ __forceinline__ float ldf(const void* p, int i) {
    if constexpr (F32) {
        return ((const float*)p)[i];
    } else {
        unsigned int u = ((const unsigned short*)p)[i];
        return __uint_as_float(u << 16);
    }
}

// 8 consecutive elements via 16B vector loads (both paths 16B-aligned for
// our offsets: DIN*elt_size multiples of 16 at row starts, offs multiple of 8)
template<bool F32>
__device__ __forceinline__ void ld8(const void* p, int elem_off, float* out) {
    if constexpr (F32) {
        const float4* q = (const float4*)((const float*)p + elem_off);
        float4 a = q[0], b = q[1];
        out[0]=a.x; out[1]=a.y; out[2]=a.z; out[3]=a.w;
        out[4]=b.x; out[5]=b.y; out[6]=b.z; out[7]=b.w;
    } else {
        const uint4* q = (const uint4*)((const unsigned short*)p + elem_off);
        uint4 a = q[0];
        out[0]=__uint_as_float(a.x << 16); out[1]=__uint_as_float(a.x & 0xFFFF0000u);
        out[2]=__uint_as_float(a.y << 16); out[3]=__uint_as_float(a.y & 0xFFFF0000u);
        out[4]=__uint_as_float(a.z << 16); out[5]=__uint_as_float(a.z & 0xFFFF0000u);
        out[6]=__uint_as_float(a.w << 16); out[7]=__uint_as_float(a.w & 0xFFFF0000u);
    }
}

// Per-wave dtype probe on raw 16-bit halves of emb (R2-proven).
__device__ __forceinline__ bool probe_f32(const void* emb) {
    unsigned short v = ((const unsigned short*)emb)[threadIdx.x & 63];
    int ex = (v >> 7) & 0xFF;
    bool bad = (ex == 0xFF) || (ex > 130) || (ex != 0 && ex < 100);
    return __popcll(__ballot(bad)) > 5;
}

// Pade [5/4] tanh: err < 3e-5 on [-2.2,2.2] (cell: |cx| <= ~2.1)
__device__ __forceinline__ float pade_tanh(float x) {
    float u = x * x;
    float num = x * fmaf(u, fmaf(u, 1.0f, 105.0f), 945.0f);
    float den = fmaf(u, fmaf(u, 15.0f, 420.0f), 945.0f);
    return num * __builtin_amdgcn_rcpf(den);
}

// Pade [3/2] tanh: err < 3.2e-4 on [-1,1] (activation: |arg| <= 1)
__device__ __forceinline__ float tanh32(float x) {
    float u = x * x;
    float num = x * (u + 15.0f);
    float den = fmaf(u, 6.0f, 15.0f);
    return num * __builtin_amdgcn_rcpf(den);
}

template<int CTRL>
__device__ __forceinline__ float dpp_shr(float x) {
    return __int_as_float(__builtin_amdgcn_update_dpp(
        0, __float_as_int(x), CTRL, 0xF, 0xF, true));
}
template<int N>
__device__ __forceinline__ float dpp_shl(float x) {
    return __int_as_float(__builtin_amdgcn_update_dpp(
        0, __float_as_int(x), 0x100 | N, 0xF, 0xF, true));
}
// row_shr:4 with multiplicative-identity masking (R4-proven)
__device__ __forceinline__ float dpp_shr4_id(float x) {
    return __int_as_float(__builtin_amdgcn_update_dpp(
        __float_as_int(1.0f), __float_as_int(x), 0x114, 0xF, 0xB, false));
}
__device__ __forceinline__ float bperm(int byteidx, float v) {
    return __int_as_float(__builtin_amdgcn_ds_bpermute(byteidx, __float_as_int(v)));
}
__device__ __forceinline__ float rdlane(float v, int l) {
    return __int_as_float(__builtin_amdgcn_readlane(__float_as_int(v), l));
}

// ---------------- Kernel 1: parallel pre-activations (R0-proven, verbatim) ----------------
// pre[t*32 + g*8 + w] = (emb_t . W_g[w,:256] + b_g[w] + th_g[w]) / 2pi
template<bool F32>
__device__ __forceinline__ void pre_body(
    const int* __restrict__ sentence, const void* __restrict__ emb,
    const void* Wf, const void* bf_, const void* Wi, const void* bi,
    const void* Wu, const void* bu, const void* Wo, const void* bo,
    const void* thf, const void* thi, const void* thu, const void* tho,
    float* __restrict__ pre, float* se)
{
    const int t = blockIdx.x;
    const int tid = threadIdx.x;
    const int row = sentence[t];
    se[tid] = ldf<F32>(emb, row * EMB + tid);
    __syncthreads();
    const int u = tid >> 3;
    const int j = tid & 7;
    const int g = u >> 3, w = u & 7;
    const void* W  = (g == 0) ? Wf  : (g == 1) ? Wi  : (g == 2) ? Wu  : Wo;
    const void* b  = (g == 0) ? bf_ : (g == 1) ? bi  : (g == 2) ? bu  : bo;
    const void* th = (g == 0) ? thf : (g == 1) ? thi : (g == 2) ? thu : tho;
    float s = 0.f;
    #pragma unroll
    for (int m = 0; m < 4; ++m) {
        const int off = j * 8 + m * 64;
        float wv[8];
        ld8<F32>(W, w * DIN + off, wv);
        #pragma unroll
        for (int i = 0; i < 8; ++i) s += se[off + i] * wv[i];
    }
    s += __shfl_xor(s, 1, 8);
    s += __shfl_xor(s, 2, 8);
    s += __shfl_xor(s, 4, 8);
    if (j == 0) pre[t * 32 + u] = (s + ldf<F32>(b, w) + ldf<F32>(th, w)) * INV2PI;
}

__global__ __launch_bounds__(256) void k_pre(
    const int* __restrict__ sentence, const void* __restrict__ emb,
    const void* Wf, const void* bf_, const void* Wi, const void* bi,
    const void* Wu, const void* bu, const void* Wo, const void* bo,
    const void* thf, const void* thi, const void* thu, const void* tho,
    float* __restrict__ pre)
{
    __shared__ float se[EMB];
    if (probe_f32(emb))
        pre_body<true >(sentence, emb, Wf, bf_, Wi, bi, Wu, bu, Wo, bo, thf, thi, thu, tho, pre, se);
    else
        pre_body<false>(sentence, emb, Wf, bf_, Wi, bi, Wu, bu, Wo, bo, thf, thi, thu, tho, pre, se);
}

// ---------------- Kernel 2: chunk recurrence + fused head ----------------
// 256 blocks x 1 wave. Block b computes outputs [8b, 8b+8) after WARM=48
// warmup steps from zero state. Per-step body identical to R0-proven loop.
// Prefetch row is clamped to SEQ-8 so all pre reads stay in-bounds (no
// reliance on workspace slack past SEQ*32 floats).
template<bool F32, bool FAST>
__device__ __forceinline__ void seq_loop_g(
    const float* __restrict__ pre, float* hlds,
    const float (&Wh)[8], int pidx, int k,
    float as, float os, float ob,
    int bfi, int bii, int bui, int boi, bool sel32, bool sel16,
    int start, int endt, int t_out)
{
    const int lane = threadIdx.x;
    const bool k1 = (k >= 1), k2 = (k >= 2);
    const bool isk0 = (k == 0);
    float h0 = 0.f, h1 = 0.f, h2 = 0.f, h3 = 0.f;
    float h4 = 0.f, h5 = 0.f, h6 = 0.f, h7 = 0.f;
    float cx = 0.f;
    float pb[8];
    {
        const float* pp = pre + start * 32 + pidx;
        #pragma unroll
        for (int i = 0; i < 8; ++i) pb[i] = pp[i * 32];
    }

    for (int tb = start; tb < endt; tb += 8) {
        // prefetch source for rows tb+8..tb+15, clamped in-bounds (tail values unused)
        const int pft = (tb + 8 <= SEQ - 8) ? (tb + 8) : (SEQ - 8);
        const float* ppn = pre + pft * 32 + pidx;
        #pragma unroll
        for (int u = 0; u < 8; ++u) {
            const int t = tb + u;
            float pv = pb[u];
            pb[u] = ppn[u * 32];   // prefetch t+8; tail reads clamped rows, unused
            // phi/2pi = pv + (Wh/2pi).h
            float a0 = fmaf(h0, Wh[0], pv);
            float a1 = fmaf(h1, Wh[1], h2 * Wh[2]);
            float a2 = fmaf(h3, Wh[3], h4 * Wh[4]);
            float a3 = fmaf(h5, Wh[5], h6 * Wh[6]);
            float phi = (a1 + a2) + (a3 + fmaf(h7, Wh[7], a0));
            float c = __builtin_amdgcn_cosf(phi);     // input in revolutions
            // inclusive product scan over 8-lane groups (row-local DPP)
            float d = c;
            float t1 = dpp_shr<0x111>(d); d *= (k1 ? t1 : 1.0f);
            float t2 = dpp_shr<0x112>(d); d *= (k2 ? t2 : 1.0f);
            d *= dpp_shr4_id(d);
            // activation: ob + os*tanh(as*outv)
            float act = fmaf(os, tanh32(d * as), ob);
            float f_, iv, uv, ov;
            if constexpr (FAST) {
                v2u r32 = __builtin_amdgcn_permlane32_swap(
                    __float_as_uint(act), __float_as_uint(act), false, false);
                float up = __uint_as_float(sel32 ? r32[1] : r32[0]); // old upper half
                float fix = dpp_shl<6>(up);              // lane 8g <- up[8g+6]
                float act0 = isk0 ? fix : act;
                v2u r16 = __builtin_amdgcn_permlane16_swap(
                    __float_as_uint(act0), __float_as_uint(act0), false, false);
                float sw = __uint_as_float(sel16 ? r16[1] : r16[0]); // row1 -> row0
                f_ = act0;               // lanes 0-7: f
                iv = dpp_shl<8>(act0);   // lanes 0-7 <- 8-15: i
                uv = sw;                 // lanes 0-7 <- 16-23: u
                ov = dpp_shl<8>(sw);     // lanes 0-7 <- 24-31: o
            } else {
                f_ = bperm(bfi, act);
                iv = bperm(bii, act);
                uv = bperm(bui, act);
                ov = bperm(boi, act);
            }
            cx = fmaf(f_, cx, iv * uv);
            float th = pade_tanh(cx);
            float hv = ov * th;
            int idx = t - t_out;                  // warm steps clamp to slot 0
            idx = idx < 0 ? 0 : idx;
            if (lane < 8) hlds[idx * 8 + lane] = hv;
            h0 = rdlane(hv, 0); h1 = rdlane(hv, 1);
            h2 = rdlane(hv, 2); h3 = rdlane(hv, 3);
            h4 = rdlane(hv, 4); h5 = rdlane(hv, 5);
            h6 = rdlane(hv, 6); h7 = rdlane(hv, 7);
        }
    }
}

template<bool F32>
__device__ __forceinline__ void seqhead_body(
    const void* Wf, const void* Wi, const void* Wu, const void* Wo,
    const float* __restrict__ pre, const void* Wt, const void* bt,
    void* __restrict__ out, float* hlds)
{
    const int lane = threadIdx.x;
    const int k = lane & 7;
    const int g = (lane >> 3) & 3;
    const int w = (lane < 32) ? k : (7 - k);
    const void* W = (g == 0) ? Wf : (g == 1) ? Wi : (g == 2) ? Wu : Wo;
    float Wh[8];
    #pragma unroll
    for (int j = 0; j < 8; ++j) Wh[j] = ldf<F32>(W, w * DIN + EMB + j) * INV2PI;
    const int pidx = (g << 3) | w;
    const float as = (g == 2) ? 1.0f : 0.5f;
    const float os = (g == 2) ? 1.0f : 0.5f;
    const float ob = (g == 2) ? 0.0f : 0.5f;
    // bperm fallback gather indices (lanes 0-7 meaningful)
    const int bfi = ((k == 0) ? 38 : k) << 2;
    const int bii = ((k == 0) ? 46 : (8 + k)) << 2;
    const int bui = ((k == 0) ? 54 : (16 + k)) << 2;
    const int boi = ((k == 0) ? 62 : (24 + k)) << 2;
    // chunk range
    const int t_out = blockIdx.x * CHLEN;
    const int start = (t_out >= WARM) ? (t_out - WARM) : 0;
    const int endt = t_out + CHLEN;

    bool fast = false, sel32 = false, sel16 = false;
#if HAVE_PLSWAP
    {
        // probe the swap builtins' result ordering with lane ids
        unsigned li = (unsigned)lane;
        v2u r = __builtin_amdgcn_permlane32_swap(li, li, false, false);
        bool gx = (lane >= 32) || (r[0] == li + 32);
        bool gy = (lane >= 32) || (r[1] == li + 32);
        bool ax = __popcll(__ballot(gx)) == 64;
        bool ay = __popcll(__ballot(gy)) == 64;
        sel32 = (!ax && ay);
        bool ok32 = ax || ay;
        v2u s = __builtin_amdgcn_permlane16_swap(li, li, false, false);
        bool rowEven = ((lane >> 4) & 1) == 0;
        bool hx = !rowEven || (s[0] == li + 16);
        bool hy = !rowEven || (s[1] == li + 16);
        bool bx = __popcll(__ballot(hx)) == 64;
        bool by = __popcll(__ballot(hy)) == 64;
        sel16 = (!bx && by);
        bool ok16 = bx || by;
        fast = ok32 && ok16;
    }
#endif
    if (fast) seq_loop_g<F32, true >(pre, hlds, Wh, pidx, k, as, os, ob,
                                     bfi, bii, bui, boi, sel32, sel16,
                                     start, endt, t_out);
    else      seq_loop_g<F32, false>(pre, hlds, Wh, pidx, k, as, os, ob,
                                     bfi, bii, bui, boi, sel32, sel16,
                                     start, endt, t_out);

    // ---- fused head + log_softmax (same wave; hlds wave-local) ----
    __builtin_amdgcn_s_waitcnt(0);   // LDS stores visible to this wave
    const int l = lane;
    float wtv[8]; float btv = 0.f;
    if (l < TAGS) {
        btv = ldf<F32>(bt, l);
        #pragma unroll
        for (int j = 0; j < 8; ++j) wtv[j] = ldf<F32>(Wt, l * 8 + j);
    } else {
        #pragma unroll
        for (int j = 0; j < 8; ++j) wtv[j] = 0.f;
    }
    #pragma unroll
    for (int tl = 0; tl < CHLEN; ++tl) {
        const int t = t_out + tl;
        float logit = -INFINITY;
        if (l < TAGS) {
            logit = btv;
            #pragma unroll
            for (int j = 0; j < 8; ++j) logit += hlds[tl * 8 + j] * wtv[j];
        }
        float m = logit;
        #pragma unroll
        for (int s = 32; s >= 1; s >>= 1) m = fmaxf(m, __shfl_xor(m, s, 64));
        float e = (l < TAGS) ? __expf(logit - m) : 0.f;
        float sum = e;
        #pragma unroll
        for (int s = 32; s >= 1; s >>= 1) sum += __shfl_xor(sum, s, 64);
        if (l < TAGS) {
            float v = logit - m - __logf(sum);
            if constexpr (F32) ((float*)out)[t * TAGS + l] = v;
            else ((unsigned short*)out)[t * TAGS + l] =
                     (unsigned short)(((__float_as_uint(v) + 0x8000u +
                                        ((__float_as_uint(v) >> 16) & 1u)) >> 16));  // RNE bf16
        }
    }
}

__global__ __launch_bounds__(64) void k_seqhead(
    const void* __restrict__ emb,
    const void* Wf, const void* Wi, const void* Wu, const void* Wo,
    const float* __restrict__ pre, const void* Wt, const void* bt,
    void* __restrict__ out)
{
    __shared__ float hlds[CHLEN * 8];   // 256 B (output steps only)
    if (probe_f32(emb)) seqhead_body<true >(Wf, Wi, Wu, Wo, pre, Wt, bt, out, hlds);
    else                seqhead_body<false>(Wf, Wi, Wu, Wo, pre, Wt, bt, out, hlds);
}

extern "C" void kernel_launch(void* const* d_in, const int* in_sizes, int n_in,
                              void* d_out, int out_size, void* d_ws, size_t ws_size,
                              hipStream_t stream) {
    (void)in_sizes; (void)n_in; (void)out_size; (void)ws_size;
    const int* sentence = (const int*)d_in[0];
    const void* emb = d_in[1];
    const void* Wf = d_in[2];  const void* bf_ = d_in[3];
    const void* Wi = d_in[4];  const void* bi = d_in[5];
    const void* Wu = d_in[6];  const void* bu = d_in[7];
    const void* Wo = d_in[8];  const void* bo = d_in[9];
    const void* thf = d_in[10]; const void* thi = d_in[11];
    const void* thu = d_in[12]; const void* tho = d_in[13];
    const void* Wt = d_in[14]; const void* bt = d_in[15];

    float* pre = (float*)d_ws;   // SEQ*32 floats; all accesses in-bounds (clamped prefetch)

    k_pre<<<dim3(SEQ), dim3(256), 0, stream>>>(sentence, emb,
        Wf, bf_, Wi, bi, Wu, bu, Wo, bo, thf, thi, thu, tho, pre);
    k_seqhead<<<dim3(NCHUNK), dim3(64), 0, stream>>>(emb,
        Wf, Wi, Wu, Wo, pre, Wt, bt, d_out);
}